// Round 1
// 289.198 us; speedup vs baseline: 1.0366x; 1.0366x over previous
//
#include <hip/hip_runtime.h>

#define Bb  512
#define Ll  64
#define NEe 128
#define Dd  128
#define NT  512
#define BLD (Bb*Ll*Dd)

typedef unsigned short ushort_t;
typedef unsigned int   uint_t;
typedef unsigned long long u64;
typedef short short8  __attribute__((ext_vector_type(8)));
typedef float floatx4 __attribute__((ext_vector_type(4)));

__device__ __forceinline__ float bf2f(ushort_t u){ return __uint_as_float(((uint_t)u)<<16); }
__device__ __forceinline__ ushort_t f2bf(float f){
  uint_t u = __float_as_uint(f);
  return (ushort_t)((u + 0x7fffu + ((u>>16)&1u)) >> 16);
}
__device__ __forceinline__ uint_t packbf(float a, float b){
  return (uint_t)f2bf(a) | ((uint_t)f2bf(b)<<16);
}
__device__ __forceinline__ float lrelu(float t){ return t > 0.f ? t : 0.2f*t; }

// -------- ws layout --------
// bytes [0, 32768): Wt bf16, Wt[m*128+k] = bf16(g2_w[k*128+m])   (W^T, row-major)
// float offset 8192: u[2][3][128]  (u1,u2,u3 per layer; batch-independent folds)
// float offset 8960: c[2]          (q . a[:d] per layer)

__global__ void prep(const float* __restrict__ g1_w2, const float* __restrict__ g1_w3,
                     const float* __restrict__ g1_q,  const float* __restrict__ g1_a,
                     const float* __restrict__ g1_a2,
                     const float* __restrict__ g2_w,  const float* __restrict__ g2_w2,
                     const float* __restrict__ g2_w3, const float* __restrict__ g2_q,
                     const float* __restrict__ g2_a,  const float* __restrict__ g2_a2,
                     void* ws){
  ushort_t* wt = (ushort_t*)ws;
  float* wsf = (float*)ws;
  const int tid = threadIdx.x, bid = blockIdx.x;
  if (bid < 8){
    // W^T bf16 transpose, 8 blocks x 2048 entries
    for (int p = bid*2048 + tid; p < (bid+1)*2048; p += 256){
      int m = p >> 7, k = p & 127;
      wt[p] = f2bf(g2_w[k*128 + m]);
    }
  } else if (bid < 14){
    // u-vector folds: job = (layer, vec); split-K over 2 half-dots
    const int job = bid - 8;
    const int l = job / 3, vec = job % 3;
    const float* w  = (vec == 2) ? (l ? g2_w3 : g1_w3) : (l ? g2_w2 : g1_w2);
    const float* av = l ? g2_a  : g1_a;
    const float* a2 = l ? g2_a2 : g1_a2;
    const float* v  = (vec == 0) ? (av + 128) : (vec == 1 ? a2 : (a2 + 128));
    __shared__ float part[256];
    const int o = tid & 127, h = tid >> 7;
    float s = 0.f;
    for (int c = h*64; c < h*64 + 64; c++) s += w[o*128 + c] * v[c];
    part[tid] = s;
    __syncthreads();
    if (tid < 128) wsf[8192 + l*384 + vec*128 + tid] = part[tid] + part[tid + 128];
  } else {
    // c1 per layer
    const int l = bid - 14;
    const float* qv = l ? g2_q : g1_q;
    const float* av = l ? g2_a : g1_a;
    if (tid < 64){
      float s = qv[tid]*av[tid] + qv[tid+64]*av[tid+64];
      #pragma unroll
      for (int off = 32; off; off >>= 1) s += __shfl_xor(s, off);
      if (tid == 0) wsf[8960 + l] = s;
    }
  }
}

// One block per batch, 8 waves, MFMA 16x16x32 bf16.
// Softmaxes are factored: att = diag(1/denom) * (mask .* broadcast(exp-vec));
// the row-scale commutes with the GEMM, so LDS tiles hold UNNORMALIZED
// mask.*exp values (pure parallel fill, no shuffle chains) and accumulators
// are scaled in the MFMA epilogue. ve (edge@u3) folds into S3's epilogue.
// No per-row max subtraction: |logits| ~ O(0.3), exp is safe; masked = 0.
//
// Memory-path notes (this round):
//  - residual f32 is staged once through LDS (edgeT reused as float[64][132])
//    into 16 regs per thread -> no stage-F global re-gather of emb (x2 layers)
//  - l==1 stage F writes fragments into the same LDS f32 buffer; a final
//    cooperative pass streams both x copies as lane-consecutive float4
//    (line-aligned, no partial-line RMW amplification)
__global__ __launch_bounds__(NT, 4)
void hgat(const int* __restrict__ gidx,
          const float* __restrict__ HT,
          const float* __restrict__ emb,
          const float* __restrict__ emb2,
          const void* __restrict__ ws,
          float* __restrict__ out)
{
  __shared__ __align__(16) ushort_t xT[128*72];      // xT[d][j], stride 72
  __shared__ __align__(16) ushort_t edgeT[128*136];  // edgeT[d][e] / tmp[e][k], stride 136
  __shared__ __align__(16) ushort_t attU[9216];      // attE'[128][72] | PN'[64][136] | f32 pf1
  __shared__ __align__(16) float pfE[128*4];         // denomE partials [e][h]
  __shared__ __align__(16) float pfN[64*8];          // denomN partials [j][h]
  __shared__ u64  adjb[128];                         // edge-major bitmask
  __shared__ u64  adjTb[128];                        // [j*2+w] node-major bitmask
  __shared__ float Ev[64], vnv[64], vev[128];
  __shared__ int   idxs[64];

  const int tid  = threadIdx.x;
  const int b    = blockIdx.x;
  const int lane = tid & 63;
  const int wave = tid >> 6;
  const int q    = lane >> 4;      // quad 0..3
  const int m15  = lane & 15;

  const ushort_t* wt  = (const ushort_t*)ws;
  const float*    wsf = (const float*)ws;
  float* pf1 = (float*)attU;
  float* resf = (float*)edgeT;     // f32 view [64][132]; 64*132*4 = 33792 <= 34816

  if (tid < 64) idxs[tid] = gidx[b*64 + tid];
  __syncthreads();

  // ---- gather: emb -> xT (transposed, bank-rotated) + resf (f32), emb2 -> out2, HT -> adjb ----
  for (int p = tid; p < 2048; p += NT){
    int j = p >> 5, c4 = p & 31;
    const float4 v = *(const float4*)(emb + (size_t)idxs[j]*128 + c4*4);
    float vals[4] = {v.x, v.y, v.z, v.w};
    #pragma unroll
    for (int t = 0; t < 4; t++){
      int tt = (t + c4) & 3;
      xT[(c4*4 + tt)*72 + j] = f2bf(vals[tt]);
    }
    *(float4*)&resf[j*132 + c4*4] = v;
    const float4 v2 = *(const float4*)(emb2 + (size_t)idxs[j]*128 + c4*4);
    *(float4*)(out + (size_t)2*BLD + (size_t)b*8192 + (size_t)p*4) = v2;
  }
  for (int i = wave; i < 128; i += 8){
    float f = HT[(size_t)b*8192 + i*64 + lane];
    u64 m = __ballot(f != 0.f);
    if (lane == 0) adjb[i] = m;
  }
  __syncthreads();

  // ---- residual into regs, F-layout: resreg[tm*4+rr] = x[16*tm+4*q+rr][16*wave+m15] ----
  float resreg[16];
  {
    const int dcol = 16*wave + m15;
    #pragma unroll
    for (int t = 0; t < 16; t++){
      int j = 16*(t >> 2) + 4*q + (t & 3);
      resreg[t] = resf[j*132 + dcol];
    }
  }
  for (int j = wave; j < 64; j += 8){
    u64 b0 = __ballot((adjb[lane]      >> j) & 1);
    u64 b1 = __ballot((adjb[lane + 64] >> j) & 1);
    if (lane == 0){ adjTb[2*j] = b0; adjTb[2*j+1] = b1; }
  }
  __syncthreads();

  for (int l = 0; l < 2; ++l){
    const float* ug  = wsf + 8192 + l*384;   // u1 | u2 | u3
    const float* u3g = ug + 256;

    // ---- A: e1/vn matvec partials ----
    {
      const int j = tid & 63, p8 = tid >> 6;
      float s1 = 0.f, s2 = 0.f;
      #pragma unroll
      for (int c = p8*16; c < p8*16 + 16; c++){
        float xv = bf2f(xT[c*72 + j]);
        s1 += xv * ug[c];
        s2 += xv * ug[128 + c];
      }
      pf1[p8*64 + j] = s1;
      pf1[512 + p8*64 + j] = s2;
    }
    __syncthreads();

    // ---- B: finalize e1 -> E = exp(lrelu(c1+s1)), vn ----
    if (tid < 64){
      float s1 = 0.f, s2 = 0.f;
      #pragma unroll
      for (int p = 0; p < 8; p++){ s1 += pf1[p*64 + tid]; s2 += pf1[512 + p*64 + tid]; }
      Ev[tid]  = __expf(lrelu(wsf[8960 + l] + s1));
      vnv[tid] = s2;
    }
    __syncthreads();

    // ---- C: attE' = mask .* E (unnormalized) + denomE partials ----
    {
      const int i  = tid >> 2;
      const int jb = (tid & 3) << 4;
      const uint_t bits = (uint_t)((adjb[i] >> jb) & 0xFFFFull);
      float sE = 0.f;
      uint_t pk[8];
      #pragma unroll
      for (int t = 0; t < 8; t++){
        float v0 = ((bits >> (2*t))   & 1) ? Ev[jb + 2*t]   : 0.f;
        float v1 = ((bits >> (2*t+1)) & 1) ? Ev[jb + 2*t+1] : 0.f;
        sE += v0 + v1;
        pk[t] = packbf(v0, v1);
      }
      *(uint4*)&attU[i*72 + jb]     = *(uint4*)&pk[0];
      *(uint4*)&attU[i*72 + jb + 8] = *(uint4*)&pk[4];
      pfE[i*4 + (tid & 3)] = sE;
    }
    __syncthreads();

    // ---- D: edge GEMM(s); scale rows by 1/denomE in epilogue; fold ve ----
    {
      const int tm = wave;
      short8 a0 = *(const short8*)&attU[(16*tm + m15)*72 + q*8];
      short8 a1 = *(const short8*)&attU[(16*tm + m15)*72 + 32 + q*8];
      float invd[4];
      #pragma unroll
      for (int rr = 0; rr < 4; rr++){
        float4 p4 = *(const float4*)&pfE[(16*tm + 4*q + rr)*4];
        invd[rr] = 1.f / (p4.x + p4.y + p4.z + p4.w);
      }
      if (l == 0){
        float u3r[8], vp[4] = {0.f,0.f,0.f,0.f};
        #pragma unroll
        for (int tn = 0; tn < 8; tn++) u3r[tn] = u3g[16*tn + m15];
        #pragma unroll
        for (int tn = 0; tn < 8; tn++){
          short8 b0 = *(const short8*)&xT[(16*tn + m15)*72 + q*8];
          short8 b1 = *(const short8*)&xT[(16*tn + m15)*72 + 32 + q*8];
          floatx4 acc = {0.f,0.f,0.f,0.f};
          acc = __builtin_amdgcn_mfma_f32_16x16x32_bf16(a0, b0, acc, 0,0,0);
          acc = __builtin_amdgcn_mfma_f32_16x16x32_bf16(a1, b1, acc, 0,0,0);
          float e0 = acc[0]*invd[0], e1 = acc[1]*invd[1];
          float e2 = acc[2]*invd[2], e3 = acc[3]*invd[3];
          vp[0] += e0*u3r[tn]; vp[1] += e1*u3r[tn];
          vp[2] += e2*u3r[tn]; vp[3] += e3*u3r[tn];
          uint2 pk; pk.x = packbf(e0, e1); pk.y = packbf(e2, e3);
          *(uint2*)&edgeT[(16*tn + m15)*136 + 16*tm + 4*q] = pk;
        }
        #pragma unroll
        for (int off = 1; off < 16; off <<= 1){
          #pragma unroll
          for (int rr = 0; rr < 4; rr++) vp[rr] += __shfl_xor(vp[rr], off);
        }
        if (m15 == 0){
          #pragma unroll
          for (int rr = 0; rr < 4; rr++) vev[16*tm + 4*q + rr] = vp[rr];
        }
      } else {
        // D-a: tmp = att_e @ x (normalized rows), row-major into edgeT buffer
        #pragma unroll
        for (int tn = 0; tn < 8; tn++){
          short8 b0 = *(const short8*)&xT[(16*tn + m15)*72 + q*8];
          short8 b1 = *(const short8*)&xT[(16*tn + m15)*72 + 32 + q*8];
          floatx4 acc = {0.f,0.f,0.f,0.f};
          acc = __builtin_amdgcn_mfma_f32_16x16x32_bf16(a0, b0, acc, 0,0,0);
          acc = __builtin_amdgcn_mfma_f32_16x16x32_bf16(a1, b1, acc, 0,0,0);
          #pragma unroll
          for (int rr = 0; rr < 4; rr++)
            edgeT[(16*tm + 4*q + rr)*136 + 16*tn + m15] = f2bf(acc[rr]*invd[rr]);
        }
        __syncthreads();
        // D-b: edge^T = W^T @ tmp^T; fold ve
        short8 bb0 = *(const short8*)&edgeT[(16*wave + m15)*136 +  0 + q*8];
        short8 bb1 = *(const short8*)&edgeT[(16*wave + m15)*136 + 32 + q*8];
        short8 bb2 = *(const short8*)&edgeT[(16*wave + m15)*136 + 64 + q*8];
        short8 bb3 = *(const short8*)&edgeT[(16*wave + m15)*136 + 96 + q*8];
        float4 u3q[8];
        #pragma unroll
        for (int t2 = 0; t2 < 8; t2++) u3q[t2] = *(const float4*)&u3g[16*t2 + 4*q];
        __syncthreads();   // everyone holds B before anyone overwrites
        float vp1 = 0.f;
        #pragma unroll
        for (int tm2 = 0; tm2 < 8; tm2++){
          floatx4 acc = {0.f,0.f,0.f,0.f};
          const ushort_t* wr = wt + (16*tm2 + m15)*128 + q*8;
          acc = __builtin_amdgcn_mfma_f32_16x16x32_bf16(*(const short8*)(wr +  0), bb0, acc, 0,0,0);
          acc = __builtin_amdgcn_mfma_f32_16x16x32_bf16(*(const short8*)(wr + 32), bb1, acc, 0,0,0);
          acc = __builtin_amdgcn_mfma_f32_16x16x32_bf16(*(const short8*)(wr + 64), bb2, acc, 0,0,0);
          acc = __builtin_amdgcn_mfma_f32_16x16x32_bf16(*(const short8*)(wr + 96), bb3, acc, 0,0,0);
          vp1 += acc[0]*u3q[tm2].x + acc[1]*u3q[tm2].y + acc[2]*u3q[tm2].z + acc[3]*u3q[tm2].w;
          #pragma unroll
          for (int rr = 0; rr < 4; rr++)
            edgeT[(16*tm2 + 4*q + rr)*136 + 16*wave + m15] = f2bf(acc[rr]);
        }
        vp1 += __shfl_xor(vp1, 16);
        vp1 += __shfl_xor(vp1, 32);
        if (q == 0) vev[16*wave + m15] = vp1;
      }
    }
    __syncthreads();

    // ---- E: PN' = mask .* exp(lrelu(vn+ve)) (unnormalized) + denomN partials ----
    {
      const int j  = tid >> 3;
      const int ib = (tid & 7) << 4;
      const uint_t bits = (uint_t)((adjTb[2*j + (ib >> 6)] >> (ib & 63)) & 0xFFFFull);
      const float vnj = vnv[j];
      float sN = 0.f;
      uint_t pk[8];
      #pragma unroll
      for (int t = 0; t < 8; t++){
        float t0 = lrelu(vnj + vev[ib + 2*t]);
        float t1 = lrelu(vnj + vev[ib + 2*t+1]);
        float v0 = ((bits >> (2*t))   & 1) ? __expf(t0) : 0.f;
        float v1 = ((bits >> (2*t+1)) & 1) ? __expf(t1) : 0.f;
        sN += v0 + v1;
        pk[t] = packbf(v0, v1);
      }
      *(uint4*)&attU[j*136 + ib]     = *(uint4*)&pk[0];
      *(uint4*)&attU[j*136 + ib + 8] = *(uint4*)&pk[4];
      pfN[j*8 + (tid & 7)] = sN;
    }
    __syncthreads();

    // ---- F: node = (att_n @ edge) + residual; scale rows by 1/denomN ----
    {
      const int tn = wave;
      short8 bb0 = *(const short8*)&edgeT[(16*tn + m15)*136 +  0 + q*8];
      short8 bb1 = *(const short8*)&edgeT[(16*tn + m15)*136 + 32 + q*8];
      short8 bb2 = *(const short8*)&edgeT[(16*tn + m15)*136 + 64 + q*8];
      short8 bb3 = *(const short8*)&edgeT[(16*tn + m15)*136 + 96 + q*8];
      if (l == 1) __syncthreads();   // everyone holds B before resf overwrites edgeT
      const int dcol = 16*tn + m15;
      #pragma unroll
      for (int tm = 0; tm < 4; tm++){
        const ushort_t* ar = &attU[(16*tm + m15)*136 + q*8];
        floatx4 acc = {0.f,0.f,0.f,0.f};
        acc = __builtin_amdgcn_mfma_f32_16x16x32_bf16(*(const short8*)(ar +  0), bb0, acc, 0,0,0);
        acc = __builtin_amdgcn_mfma_f32_16x16x32_bf16(*(const short8*)(ar + 32), bb1, acc, 0,0,0);
        acc = __builtin_amdgcn_mfma_f32_16x16x32_bf16(*(const short8*)(ar + 64), bb2, acc, 0,0,0);
        acc = __builtin_amdgcn_mfma_f32_16x16x32_bf16(*(const short8*)(ar + 96), bb3, acc, 0,0,0);
        float v[4];
        #pragma unroll
        for (int rr = 0; rr < 4; rr++){
          int j = 16*tm + 4*q + rr;
          float4 n0 = *(const float4*)&pfN[j*8];
          float4 n1 = *(const float4*)&pfN[j*8 + 4];
          float invn = 1.f / (n0.x+n0.y+n0.z+n0.w + n1.x+n1.y+n1.z+n1.w);
          v[rr] = acc[rr]*invn + resreg[tm*4 + rr];
        }
        if (l == 0){
          uint2 pk; pk.x = packbf(v[0], v[1]); pk.y = packbf(v[2], v[3]);
          *(uint2*)&xT[dcol*72 + 16*tm + 4*q] = pk;
        } else {
          #pragma unroll
          for (int rr = 0; rr < 4; rr++)
            resf[(16*tm + 4*q + rr)*132 + dcol] = v[rr];
        }
      }
    }
    __syncthreads();
  }

  // ---- coalesced writeout of both x copies from LDS ----
  for (int p = tid; p < 2048; p += NT){
    int j = p >> 5, c4 = p & 31;
    const float4 w = *(const float4*)&resf[j*132 + c4*4];
    size_t o = (size_t)b*8192 + (size_t)p*4;
    *(float4*)(out + o)       = w;
    *(float4*)(out + BLD + o) = w;
  }
}

extern "C" void kernel_launch(void* const* d_in, const int* in_sizes, int n_in,
                              void* d_out, int out_size, void* d_ws, size_t ws_size,
                              hipStream_t stream){
  (void)in_sizes; (void)n_in; (void)out_size; (void)ws_size;
  // setup_inputs order: 0 inputs, 1 HT, 2 G, 3 EG, 4 emb, 5 emb2,
  //                     6 g1_w2, 7 g1_w3, 8 g1_q, 9 g1_a, 10 g1_a2,
  //                     11 g2_w, 12 g2_w2, 13 g2_w3, 14 g2_q, 15 g2_a, 16 g2_a2
  prep<<<dim3(16), dim3(256), 0, stream>>>(
      (const float*)d_in[6],  (const float*)d_in[7],  (const float*)d_in[8],
      (const float*)d_in[9],  (const float*)d_in[10],
      (const float*)d_in[11], (const float*)d_in[12], (const float*)d_in[13],
      (const float*)d_in[14], (const float*)d_in[15], (const float*)d_in[16],
      d_ws);
  hgat<<<dim3(Bb), dim3(NT), 0, stream>>>(
      (const int*)d_in[0],
      (const float*)d_in[1],
      (const float*)d_in[4],
      (const float*)d_in[5],
      d_ws,
      (float*)d_out);
}

// Round 2
// 283.977 us; speedup vs baseline: 1.0556x; 1.0184x over previous
//
#include <hip/hip_runtime.h>

#define Bb  512
#define Ll  64
#define NEe 128
#define Dd  128
#define NT  512
#define BLD (Bb*Ll*Dd)

typedef unsigned short ushort_t;
typedef unsigned int   uint_t;
typedef unsigned long long u64;
typedef short short8  __attribute__((ext_vector_type(8)));
typedef float floatx4 __attribute__((ext_vector_type(4)));

__device__ __forceinline__ float bf2f(ushort_t u){ return __uint_as_float(((uint_t)u)<<16); }
__device__ __forceinline__ ushort_t f2bf(float f){
  uint_t u = __float_as_uint(f);
  return (ushort_t)((u + 0x7fffu + ((u>>16)&1u)) >> 16);
}
__device__ __forceinline__ uint_t packbf(float a, float b){
  return (uint_t)f2bf(a) | ((uint_t)f2bf(b)<<16);
}
__device__ __forceinline__ float lrelu(float t){ return t > 0.f ? t : 0.2f*t; }

// -------- ws layout --------
// bytes [0, 32768): Wt bf16, Wt[m*128+k] = bf16(g2_w[k*128+m])   (W^T, row-major)
// float offset 8192: u[2][3][128]  (u1,u2,u3 per layer; batch-independent folds)
// float offset 8960: c[2]          (q . a[:d] per layer)

__global__ void prep(const float* __restrict__ g1_w2, const float* __restrict__ g1_w3,
                     const float* __restrict__ g1_q,  const float* __restrict__ g1_a,
                     const float* __restrict__ g1_a2,
                     const float* __restrict__ g2_w,  const float* __restrict__ g2_w2,
                     const float* __restrict__ g2_w3, const float* __restrict__ g2_q,
                     const float* __restrict__ g2_a,  const float* __restrict__ g2_a2,
                     void* ws){
  ushort_t* wt = (ushort_t*)ws;
  float* wsf = (float*)ws;
  const int tid = threadIdx.x, bid = blockIdx.x;
  if (bid < 8){
    for (int p = bid*2048 + tid; p < (bid+1)*2048; p += 256){
      int m = p >> 7, k = p & 127;
      wt[p] = f2bf(g2_w[k*128 + m]);
    }
  } else if (bid < 14){
    const int job = bid - 8;
    const int l = job / 3, vec = job % 3;
    const float* w  = (vec == 2) ? (l ? g2_w3 : g1_w3) : (l ? g2_w2 : g1_w2);
    const float* av = l ? g2_a  : g1_a;
    const float* a2 = l ? g2_a2 : g1_a2;
    const float* v  = (vec == 0) ? (av + 128) : (vec == 1 ? a2 : (a2 + 128));
    __shared__ float part[256];
    const int o = tid & 127, h = tid >> 7;
    float s = 0.f;
    for (int c = h*64; c < h*64 + 64; c++) s += w[o*128 + c] * v[c];
    part[tid] = s;
    __syncthreads();
    if (tid < 128) wsf[8192 + l*384 + vec*128 + tid] = part[tid] + part[tid + 128];
  } else {
    const int l = bid - 14;
    const float* qv = l ? g2_q : g1_q;
    const float* av = l ? g2_a : g1_a;
    if (tid < 64){
      float s = qv[tid]*av[tid] + qv[tid+64]*av[tid+64];
      #pragma unroll
      for (int off = 32; off; off >>= 1) s += __shfl_xor(s, off);
      if (tid == 0) wsf[8960 + l] = s;
    }
  }
}

// One block per batch, 8 waves, MFMA 16x16x32 bf16. Latency-bound phase chain
// shortened this round:
//  - attE' (mask.*Ev) is built IN REGISTERS inside stage D from adjb bits +
//    packed-bf16 Ev: stage C, its 18KB LDS tile, and one barrier are gone.
//  - softmax denominators via ones-column MFMA: denom = att' @ ones lands in
//    exactly the acc rows the epilogue scales -> pfE/pfN and their LDS
//    reductions are gone.
//  - A+B fused into one wave-local phase (8 lanes per row, shfl_xor reduce);
//    lane map j=wave*8+(lane&7), c=h+8*cc keeps LDS reads 2-way (free).
__global__ __launch_bounds__(NT, 4)
void hgat(const int* __restrict__ gidx,
          const float* __restrict__ HT,
          const float* __restrict__ emb,
          const float* __restrict__ emb2,
          const void* __restrict__ ws,
          float* __restrict__ out)
{
  __shared__ __align__(16) ushort_t xT[128*72];      // xT[d][j], stride 72
  __shared__ __align__(16) ushort_t edgeT[128*136];  // edgeT[d][e] / tmp[e][k] / resf
  __shared__ __align__(16) ushort_t attU[64*136];    // PN'[64][136]
  __shared__ __align__(16) ushort_t EvpU[64];        // bf16(Ev[j])
  __shared__ u64  adjb[128];                         // edge-major bitmask
  __shared__ u64  adjTb[128];                        // [j*2+w] node-major bitmask
  __shared__ float vnv[64], vev[128];
  __shared__ int   idxs[64];

  const int tid  = threadIdx.x;
  const int b    = blockIdx.x;
  const int lane = tid & 63;
  const int wave = tid >> 6;
  const int q    = lane >> 4;      // quad 0..3
  const int m15  = lane & 15;

  const ushort_t* wt  = (const ushort_t*)ws;
  const float*    wsf = (const float*)ws;
  float* resf = (float*)edgeT;     // f32 view [64][132]; 64*132*4 = 33792 <= 34816

  short8 ones;
  #pragma unroll
  for (int t = 0; t < 8; t++) ones[t] = (short)0x3F80;  // bf16 1.0

  if (tid < 64) idxs[tid] = gidx[b*64 + tid];
  __syncthreads();

  // ---- gather: emb -> xT (transposed, bank-rotated) + resf (f32), emb2 -> out2, HT -> adjb ----
  for (int p = tid; p < 2048; p += NT){
    int j = p >> 5, c4 = p & 31;
    const float4 v = *(const float4*)(emb + (size_t)idxs[j]*128 + c4*4);
    float vals[4] = {v.x, v.y, v.z, v.w};
    #pragma unroll
    for (int t = 0; t < 4; t++){
      int tt = (t + c4) & 3;
      xT[(c4*4 + tt)*72 + j] = f2bf(vals[tt]);
    }
    *(float4*)&resf[j*132 + c4*4] = v;
    const float4 v2 = *(const float4*)(emb2 + (size_t)idxs[j]*128 + c4*4);
    *(float4*)(out + (size_t)2*BLD + (size_t)b*8192 + (size_t)p*4) = v2;
  }
  for (int i = wave; i < 128; i += 8){
    float f = HT[(size_t)b*8192 + i*64 + lane];
    u64 m = __ballot(f != 0.f);
    if (lane == 0) adjb[i] = m;
  }
  __syncthreads();

  // ---- residual into regs, F-layout: resreg[tm*4+rr] = x[16*tm+4*q+rr][16*wave+m15] ----
  float resreg[16];
  {
    const int dcol = 16*wave + m15;
    #pragma unroll
    for (int t = 0; t < 16; t++){
      int j = 16*(t >> 2) + 4*q + (t & 3);
      resreg[t] = resf[j*132 + dcol];
    }
  }
  for (int j = wave; j < 64; j += 8){
    u64 b0 = __ballot((adjb[lane]      >> j) & 1);
    u64 b1 = __ballot((adjb[lane + 64] >> j) & 1);
    if (lane == 0){ adjTb[2*j] = b0; adjTb[2*j+1] = b1; }
  }
  __syncthreads();

  for (int l = 0; l < 2; ++l){
    const float* ug  = wsf + 8192 + l*384;   // u1 | u2 | u3
    const float* u3g = ug + 256;

    // ---- AB (fused): s1 = x@u1, s2 = x@u2; Ev = exp(lrelu(c1+s1)) packed bf16 ----
    {
      const int j = wave*8 + (lane & 7);
      const int h = lane >> 3;
      float s1 = 0.f, s2 = 0.f;
      #pragma unroll
      for (int cc = 0; cc < 16; cc++){
        const int c = h + cc*8;
        float xv = bf2f(xT[c*72 + j]);
        s1 += xv * ug[c];
        s2 += xv * ug[128 + c];
      }
      s1 += __shfl_xor(s1, 8);  s2 += __shfl_xor(s2, 8);
      s1 += __shfl_xor(s1, 16); s2 += __shfl_xor(s2, 16);
      s1 += __shfl_xor(s1, 32); s2 += __shfl_xor(s2, 32);
      if (h == 0){
        EvpU[j] = f2bf(__expf(lrelu(wsf[8960 + l] + s1)));
        vnv[j]  = s2;
      }
    }
    __syncthreads();

    // ---- D: edge GEMM(s); A-frags + denomE built in registers; fold ve ----
    {
      const int tm = wave;
      const int r  = 16*tm + m15;                 // A-operand row this lane holds
      const u64 wb = adjb[r];
      const uint_t bits0 = (uint_t)(wb >> (q*8)) & 0xFFu;
      const uint_t bits1 = (uint_t)(wb >> (32 + q*8)) & 0xFFu;
      const uint4 ev0 = *(const uint4*)&EvpU[q*8];
      const uint4 ev1 = *(const uint4*)&EvpU[32 + q*8];
      union { uint_t u[4]; short8 s; } A0, A1;
      const uint_t e0a[4] = {ev0.x, ev0.y, ev0.z, ev0.w};
      const uint_t e1a[4] = {ev1.x, ev1.y, ev1.z, ev1.w};
      #pragma unroll
      for (int t = 0; t < 4; t++){
        uint_t m0 = (((bits0>>(2*t))&1u)   ? 0x0000FFFFu : 0u)
                  | (((bits0>>(2*t+1))&1u) ? 0xFFFF0000u : 0u);
        uint_t m1 = (((bits1>>(2*t))&1u)   ? 0x0000FFFFu : 0u)
                  | (((bits1>>(2*t+1))&1u) ? 0xFFFF0000u : 0u);
        A0.u[t] = e0a[t] & m0;
        A1.u[t] = e1a[t] & m1;
      }
      const short8 a0 = A0.s, a1 = A1.s;
      floatx4 accD = {0.f,0.f,0.f,0.f};
      accD = __builtin_amdgcn_mfma_f32_16x16x32_bf16(a0, ones, accD, 0,0,0);
      accD = __builtin_amdgcn_mfma_f32_16x16x32_bf16(a1, ones, accD, 0,0,0);
      float invd[4];
      #pragma unroll
      for (int rr = 0; rr < 4; rr++) invd[rr] = 1.f / accD[rr];

      if (l == 0){
        float u3r[8], vp[4] = {0.f,0.f,0.f,0.f};
        #pragma unroll
        for (int tn = 0; tn < 8; tn++) u3r[tn] = u3g[16*tn + m15];
        #pragma unroll
        for (int tn = 0; tn < 8; tn++){
          short8 b0 = *(const short8*)&xT[(16*tn + m15)*72 + q*8];
          short8 b1 = *(const short8*)&xT[(16*tn + m15)*72 + 32 + q*8];
          floatx4 acc = {0.f,0.f,0.f,0.f};
          acc = __builtin_amdgcn_mfma_f32_16x16x32_bf16(a0, b0, acc, 0,0,0);
          acc = __builtin_amdgcn_mfma_f32_16x16x32_bf16(a1, b1, acc, 0,0,0);
          float e0 = acc[0]*invd[0], e1 = acc[1]*invd[1];
          float e2 = acc[2]*invd[2], e3 = acc[3]*invd[3];
          vp[0] += e0*u3r[tn]; vp[1] += e1*u3r[tn];
          vp[2] += e2*u3r[tn]; vp[3] += e3*u3r[tn];
          uint2 pk; pk.x = packbf(e0, e1); pk.y = packbf(e2, e3);
          *(uint2*)&edgeT[(16*tn + m15)*136 + 16*tm + 4*q] = pk;
        }
        #pragma unroll
        for (int off = 1; off < 16; off <<= 1){
          #pragma unroll
          for (int rr = 0; rr < 4; rr++) vp[rr] += __shfl_xor(vp[rr], off);
        }
        if (m15 == 0){
          #pragma unroll
          for (int rr = 0; rr < 4; rr++) vev[16*tm + 4*q + rr] = vp[rr];
        }
      } else {
        // D-a: tmp = att_e @ x (normalized rows), row-major into edgeT buffer
        #pragma unroll
        for (int tn = 0; tn < 8; tn++){
          short8 b0 = *(const short8*)&xT[(16*tn + m15)*72 + q*8];
          short8 b1 = *(const short8*)&xT[(16*tn + m15)*72 + 32 + q*8];
          floatx4 acc = {0.f,0.f,0.f,0.f};
          acc = __builtin_amdgcn_mfma_f32_16x16x32_bf16(a0, b0, acc, 0,0,0);
          acc = __builtin_amdgcn_mfma_f32_16x16x32_bf16(a1, b1, acc, 0,0,0);
          #pragma unroll
          for (int rr = 0; rr < 4; rr++)
            edgeT[(16*tm + 4*q + rr)*136 + 16*tn + m15] = f2bf(acc[rr]*invd[rr]);
        }
        __syncthreads();
        // D-b: edge^T = W^T @ tmp^T; fold ve
        short8 bb0 = *(const short8*)&edgeT[(16*wave + m15)*136 +  0 + q*8];
        short8 bb1 = *(const short8*)&edgeT[(16*wave + m15)*136 + 32 + q*8];
        short8 bb2 = *(const short8*)&edgeT[(16*wave + m15)*136 + 64 + q*8];
        short8 bb3 = *(const short8*)&edgeT[(16*wave + m15)*136 + 96 + q*8];
        float4 u3q[8];
        #pragma unroll
        for (int t2 = 0; t2 < 8; t2++) u3q[t2] = *(const float4*)&u3g[16*t2 + 4*q];
        __syncthreads();   // everyone holds B before anyone overwrites
        float vp1 = 0.f;
        #pragma unroll
        for (int tm2 = 0; tm2 < 8; tm2++){
          floatx4 acc = {0.f,0.f,0.f,0.f};
          const ushort_t* wr = wt + (16*tm2 + m15)*128 + q*8;
          acc = __builtin_amdgcn_mfma_f32_16x16x32_bf16(*(const short8*)(wr +  0), bb0, acc, 0,0,0);
          acc = __builtin_amdgcn_mfma_f32_16x16x32_bf16(*(const short8*)(wr + 32), bb1, acc, 0,0,0);
          acc = __builtin_amdgcn_mfma_f32_16x16x32_bf16(*(const short8*)(wr + 64), bb2, acc, 0,0,0);
          acc = __builtin_amdgcn_mfma_f32_16x16x32_bf16(*(const short8*)(wr + 96), bb3, acc, 0,0,0);
          vp1 += acc[0]*u3q[tm2].x + acc[1]*u3q[tm2].y + acc[2]*u3q[tm2].z + acc[3]*u3q[tm2].w;
          #pragma unroll
          for (int rr = 0; rr < 4; rr++)
            edgeT[(16*tm2 + 4*q + rr)*136 + 16*wave + m15] = f2bf(acc[rr]);
        }
        vp1 += __shfl_xor(vp1, 16);
        vp1 += __shfl_xor(vp1, 32);
        if (q == 0) vev[16*wave + m15] = vp1;
      }
    }
    __syncthreads();

    // ---- E: PN' = mask .* exp(lrelu(vn+ve)) (unnormalized) ----
    {
      const int j  = tid >> 3;
      const int ib = (tid & 7) << 4;
      const uint_t bits = (uint_t)((adjTb[2*j + (ib >> 6)] >> (ib & 63)) & 0xFFFFull);
      const float vnj = vnv[j];
      uint_t pk[8];
      #pragma unroll
      for (int t = 0; t < 8; t++){
        float t0 = lrelu(vnj + vev[ib + 2*t]);
        float t1 = lrelu(vnj + vev[ib + 2*t+1]);
        float v0 = ((bits >> (2*t))   & 1) ? __expf(t0) : 0.f;
        float v1 = ((bits >> (2*t+1)) & 1) ? __expf(t1) : 0.f;
        pk[t] = packbf(v0, v1);
      }
      *(uint4*)&attU[j*136 + ib]     = *(uint4*)&pk[0];
      *(uint4*)&attU[j*136 + ib + 8] = *(uint4*)&pk[4];
    }
    __syncthreads();

    // ---- F: node = (att_n @ edge) + residual; denomN via ones-MFMA ----
    {
      const int tn = wave;
      short8 bb0 = *(const short8*)&edgeT[(16*tn + m15)*136 +  0 + q*8];
      short8 bb1 = *(const short8*)&edgeT[(16*tn + m15)*136 + 32 + q*8];
      short8 bb2 = *(const short8*)&edgeT[(16*tn + m15)*136 + 64 + q*8];
      short8 bb3 = *(const short8*)&edgeT[(16*tn + m15)*136 + 96 + q*8];
      if (l == 1) __syncthreads();   // everyone holds B before resf overwrites edgeT
      const int dcol = 16*tn + m15;
      #pragma unroll
      for (int tm = 0; tm < 4; tm++){
        const ushort_t* ar = &attU[(16*tm + m15)*136 + q*8];
        const short8 p0 = *(const short8*)(ar +  0);
        const short8 p1 = *(const short8*)(ar + 32);
        const short8 p2 = *(const short8*)(ar + 64);
        const short8 p3 = *(const short8*)(ar + 96);
        floatx4 acc  = {0.f,0.f,0.f,0.f};
        floatx4 accN = {0.f,0.f,0.f,0.f};
        acc  = __builtin_amdgcn_mfma_f32_16x16x32_bf16(p0, bb0, acc, 0,0,0);
        acc  = __builtin_amdgcn_mfma_f32_16x16x32_bf16(p1, bb1, acc, 0,0,0);
        acc  = __builtin_amdgcn_mfma_f32_16x16x32_bf16(p2, bb2, acc, 0,0,0);
        acc  = __builtin_amdgcn_mfma_f32_16x16x32_bf16(p3, bb3, acc, 0,0,0);
        accN = __builtin_amdgcn_mfma_f32_16x16x32_bf16(p0, ones, accN, 0,0,0);
        accN = __builtin_amdgcn_mfma_f32_16x16x32_bf16(p1, ones, accN, 0,0,0);
        accN = __builtin_amdgcn_mfma_f32_16x16x32_bf16(p2, ones, accN, 0,0,0);
        accN = __builtin_amdgcn_mfma_f32_16x16x32_bf16(p3, ones, accN, 0,0,0);
        float v[4];
        #pragma unroll
        for (int rr = 0; rr < 4; rr++)
          v[rr] = acc[rr]*(1.f/accN[rr]) + resreg[tm*4 + rr];
        if (l == 0){
          uint2 pk; pk.x = packbf(v[0], v[1]); pk.y = packbf(v[2], v[3]);
          *(uint2*)&xT[dcol*72 + 16*tm + 4*q] = pk;
        } else {
          #pragma unroll
          for (int rr = 0; rr < 4; rr++)
            resf[(16*tm + 4*q + rr)*132 + dcol] = v[rr];
        }
      }
    }
    __syncthreads();
  }

  // ---- coalesced writeout of both x copies from LDS ----
  for (int p = tid; p < 2048; p += NT){
    int j = p >> 5, c4 = p & 31;
    const float4 w = *(const float4*)&resf[j*132 + c4*4];
    size_t o = (size_t)b*8192 + (size_t)p*4;
    *(float4*)(out + o)       = w;
    *(float4*)(out + BLD + o) = w;
  }
}

extern "C" void kernel_launch(void* const* d_in, const int* in_sizes, int n_in,
                              void* d_out, int out_size, void* d_ws, size_t ws_size,
                              hipStream_t stream){
  (void)in_sizes; (void)n_in; (void)out_size; (void)ws_size;
  // setup_inputs order: 0 inputs, 1 HT, 2 G, 3 EG, 4 emb, 5 emb2,
  //                     6 g1_w2, 7 g1_w3, 8 g1_q, 9 g1_a, 10 g1_a2,
  //                     11 g2_w, 12 g2_w2, 13 g2_w3, 14 g2_q, 15 g2_a, 16 g2_a2
  prep<<<dim3(16), dim3(256), 0, stream>>>(
      (const float*)d_in[6],  (const float*)d_in[7],  (const float*)d_in[8],
      (const float*)d_in[9],  (const float*)d_in[10],
      (const float*)d_in[11], (const float*)d_in[12], (const float*)d_in[13],
      (const float*)d_in[14], (const float*)d_in[15], (const float*)d_in[16],
      d_ws);
  hgat<<<dim3(Bb), dim3(NT), 0, stream>>>(
      (const int*)d_in[0],
      (const float*)d_in[1],
      (const float*)d_in[4],
      (const float*)d_in[5],
      d_ws,
      (float*)d_out);
}

// Round 4
// 268.739 us; speedup vs baseline: 1.1155x; 1.0567x over previous
//
#include <hip/hip_runtime.h>

#define Bb  512
#define Ll  64
#define NEe 128
#define Dd  128
#define NT  512
#define BLD (Bb*Ll*Dd)

typedef unsigned short ushort_t;
typedef unsigned int   uint_t;
typedef unsigned long long u64;
typedef short short8  __attribute__((ext_vector_type(8)));
typedef float floatx4 __attribute__((ext_vector_type(4)));

__device__ __forceinline__ float bf2f(ushort_t u){ return __uint_as_float(((uint_t)u)<<16); }
__device__ __forceinline__ ushort_t f2bf(float f){
  uint_t u = __float_as_uint(f);
  return (ushort_t)((u + 0x7fffu + ((u>>16)&1u)) >> 16);
}
__device__ __forceinline__ uint_t packbf(float a, float b){
  return (uint_t)f2bf(a) | ((uint_t)f2bf(b)<<16);
}
__device__ __forceinline__ float lrelu(float t){ return t > 0.f ? t : 0.2f*t; }

// -------- ws layout --------
// bytes [0, 32768): Wt bf16, Wt[m*128+k] = bf16(g2_w[k*128+m])   (W^T, row-major)
// float offset 8192: u[2][3][128]  (u1,u2,u3 per layer). l=1's "u3" slot holds
//                    u3eff = g2_w @ (g2_w3 @ a2hi)  (ve re-association fold)
// float offset 8960: c[2]          (q . a[:d] per layer)

__global__ void prep(const float* __restrict__ g1_w2, const float* __restrict__ g1_w3,
                     const float* __restrict__ g1_q,  const float* __restrict__ g1_a,
                     const float* __restrict__ g1_a2,
                     const float* __restrict__ g2_w,  const float* __restrict__ g2_w2,
                     const float* __restrict__ g2_w3, const float* __restrict__ g2_q,
                     const float* __restrict__ g2_a,  const float* __restrict__ g2_a2,
                     void* ws){
  ushort_t* wt = (ushort_t*)ws;
  float* wsf = (float*)ws;
  const int tid = threadIdx.x, bid = blockIdx.x;
  if (bid < 8){
    for (int p = bid*2048 + tid; p < (bid+1)*2048; p += 256){
      int m = p >> 7, k = p & 127;
      wt[p] = f2bf(g2_w[k*128 + m]);
    }
  } else if (bid < 13){
    // u-vector folds: jobs (l,vec) = (0,0),(0,1),(0,2),(1,0),(1,1)
    const int job = bid - 8;
    const int l   = (job >= 3);
    const int vec = l ? (job - 3) : job;
    const float* w  = (vec == 2) ? (l ? g2_w3 : g1_w3) : (l ? g2_w2 : g1_w2);
    const float* av = l ? g2_a  : g1_a;
    const float* a2 = l ? g2_a2 : g1_a2;
    const float* v  = (vec == 0) ? (av + 128) : (vec == 1 ? a2 : (a2 + 128));
    __shared__ float part[256];
    const int o = tid & 127, h = tid >> 7;
    float s = 0.f;
    for (int c = h*64; c < h*64 + 64; c++) s += w[o*128 + c] * v[c];
    part[tid] = s;
    __syncthreads();
    if (tid < 128) wsf[8192 + l*384 + vec*128 + tid] = part[tid] + part[tid + 128];
  } else if (bid == 13){
    // u3eff (layer 1): t = g2_w3 @ a2hi, then u3eff = g2_w @ t
    __shared__ float t[128];
    if (tid < 128){
      float s = 0.f;
      for (int c = 0; c < 128; c++) s += g2_w3[tid*128 + c] * g2_a2[128 + c];
      t[tid] = s;
    }
    __syncthreads();
    if (tid < 128){
      float s = 0.f;
      for (int m = 0; m < 128; m++) s += g2_w[tid*128 + m] * t[m];
      wsf[8192 + 384 + 256 + tid] = s;
    }
  } else {
    const int l = bid - 14;
    const float* qv = l ? g2_q : g1_q;
    const float* av = l ? g2_a : g1_a;
    if (tid < 64){
      float s = qv[tid]*av[tid] + qv[tid+64]*av[tid+64];
      #pragma unroll
      for (int off = 32; off; off >>= 1) s += __shfl_xor(s, off);
      if (tid == 0) wsf[8960 + l] = s;
    }
  }
}

// One block per batch, 8 waves, MFMA 16x16x32 bf16. Phase chain (the binding
// constraint: 512 blocks = 2/CU all co-resident, nothing >21% busy):
//   gather -> [ AB -> D -> E -> F1 (-> F2 l1) ] x2 -> writeout
// Layer-1 GEMM chain re-associated: node = (att_n@tmp)@W and ve = tmp@(W@u3)
// -- so D is IDENTICAL for both layers (D-b eliminated: -2 barriers, -32 MFMA,
// -1 LDS round trip), and a light F2 (16 MFMA, B-frags straight from global
// wt) finishes layer 1. idxs LDS + 2 preamble barriers also removed.
// Barriers/block: 14 -> 10.
__global__ __launch_bounds__(NT, 4)
void hgat(const int* __restrict__ gidx,
          const float* __restrict__ HT,
          const float* __restrict__ emb,
          const float* __restrict__ emb2,
          const void* __restrict__ ws,
          float* __restrict__ out)
{
  __shared__ __align__(16) ushort_t xT[128*72];      // xT[d][j] stride 72; l1-F1 reuses as Gbuf[64][136]
  __shared__ __align__(16) ushort_t edgeT[128*136];  // tmp^T[d][e]; also resf f32 view
  __shared__ __align__(16) ushort_t attU[64*136];    // PN'[64][136]
  __shared__ __align__(16) ushort_t EvpU[64];        // bf16(Ev[j])
  __shared__ u64  adjb[128];                         // edge-major bitmask
  __shared__ u64  adjTb[128];                        // [j*2+w] node-major bitmask
  __shared__ float vnv[64], vev[128];

  const int tid  = threadIdx.x;
  const int b    = blockIdx.x;
  const int lane = tid & 63;
  const int wave = tid >> 6;
  const int q    = lane >> 4;      // quad 0..3
  const int m15  = lane & 15;

  const ushort_t* wt  = (const ushort_t*)ws;
  const float*    wsf = (const float*)ws;
  float* resf = (float*)edgeT;     // f32 view [64][132]; 64*132*4 = 33792 <= 34816
  ushort_t* Gbuf = &xT[0];         // l1 F1 output G[j][k] stride 136; 64*136 <= 128*72

  short8 ones;
  #pragma unroll
  for (int t = 0; t < 8; t++) ones[t] = (short)0x3F80;  // bf16 1.0

  // ---- gather: emb -> xT (transposed, bank-rotated) + resf (f32), emb2 -> out2, HT -> adjb ----
  const int* gb = gidx + b*64;
  for (int p = tid; p < 2048; p += NT){
    int j = p >> 5, c4 = p & 31;
    const int idx = gb[j];
    const float4 v = *(const float4*)(emb + (size_t)idx*128 + c4*4);
    float vals[4] = {v.x, v.y, v.z, v.w};
    #pragma unroll
    for (int t = 0; t < 4; t++){
      int tt = (t + c4) & 3;
      xT[(c4*4 + tt)*72 + j] = f2bf(vals[tt]);
    }
    *(float4*)&resf[j*132 + c4*4] = v;
    const float4 v2 = *(const float4*)(emb2 + (size_t)idx*128 + c4*4);
    *(float4*)(out + (size_t)2*BLD + (size_t)b*8192 + (size_t)p*4) = v2;
  }
  for (int i = wave; i < 128; i += 8){
    float f = HT[(size_t)b*8192 + i*64 + lane];
    u64 m = __ballot(f != 0.f);
    if (lane == 0) adjb[i] = m;
  }
  __syncthreads();

  // ---- residual into regs (F-layout) + adjT bitmask; no trailing barrier:
  //      first consumer of edgeT/adjTb is after the AB sync ----
  float resreg[16];
  {
    const int dcol = 16*wave + m15;
    #pragma unroll
    for (int t = 0; t < 16; t++){
      int j = 16*(t >> 2) + 4*q + (t & 3);
      resreg[t] = resf[j*132 + dcol];
    }
  }
  for (int j = wave; j < 64; j += 8){
    u64 b0 = __ballot((adjb[lane]      >> j) & 1);
    u64 b1 = __ballot((adjb[lane + 64] >> j) & 1);
    if (lane == 0){ adjTb[2*j] = b0; adjTb[2*j+1] = b1; }
  }

  for (int l = 0; l < 2; ++l){
    const float* ug  = wsf + 8192 + l*384;   // u1 | u2 | u3(eff)
    const float* u3g = ug + 256;

    // ---- AB (fused): s1 = x@u1, s2 = x@u2; Ev = exp(lrelu(c1+s1)) packed bf16 ----
    {
      const int j = wave*8 + (lane & 7);
      const int h = lane >> 3;
      float s1 = 0.f, s2 = 0.f;
      #pragma unroll
      for (int cc = 0; cc < 16; cc++){
        const int c = h + cc*8;
        float xv = bf2f(xT[c*72 + j]);
        s1 += xv * ug[c];
        s2 += xv * ug[128 + c];
      }
      s1 += __shfl_xor(s1, 8);  s2 += __shfl_xor(s2, 8);
      s1 += __shfl_xor(s1, 16); s2 += __shfl_xor(s2, 16);
      s1 += __shfl_xor(s1, 32); s2 += __shfl_xor(s2, 32);
      if (h == 0){
        EvpU[j] = f2bf(__expf(lrelu(wsf[8960 + l] + s1)));
        vnv[j]  = s2;
      }
    }
    __syncthreads();

    // ---- D (both layers): tmp^T = (att_e_norm @ x)^T; A-frags + denomE in
    //      registers; ve = tmp_norm @ u3(eff) folded via shuffle ----
    {
      const int tm = wave;
      const int r  = 16*tm + m15;
      const u64 wb = adjb[r];
      const uint_t bits0 = (uint_t)(wb >> (q*8)) & 0xFFu;
      const uint_t bits1 = (uint_t)(wb >> (32 + q*8)) & 0xFFu;
      const uint4 ev0 = *(const uint4*)&EvpU[q*8];
      const uint4 ev1 = *(const uint4*)&EvpU[32 + q*8];
      union { uint_t u[4]; short8 s; } A0, A1;
      const uint_t e0a[4] = {ev0.x, ev0.y, ev0.z, ev0.w};
      const uint_t e1a[4] = {ev1.x, ev1.y, ev1.z, ev1.w};
      #pragma unroll
      for (int t = 0; t < 4; t++){
        uint_t m0 = (((bits0>>(2*t))&1u)   ? 0x0000FFFFu : 0u)
                  | (((bits0>>(2*t+1))&1u) ? 0xFFFF0000u : 0u);
        uint_t m1 = (((bits1>>(2*t))&1u)   ? 0x0000FFFFu : 0u)
                  | (((bits1>>(2*t+1))&1u) ? 0xFFFF0000u : 0u);
        A0.u[t] = e0a[t] & m0;
        A1.u[t] = e1a[t] & m1;
      }
      const short8 a0 = A0.s, a1 = A1.s;
      floatx4 accD = {0.f,0.f,0.f,0.f};
      accD = __builtin_amdgcn_mfma_f32_16x16x32_bf16(a0, ones, accD, 0,0,0);
      accD = __builtin_amdgcn_mfma_f32_16x16x32_bf16(a1, ones, accD, 0,0,0);
      float invd[4];
      #pragma unroll
      for (int rr = 0; rr < 4; rr++) invd[rr] = 1.f / accD[rr];

      float u3r[8], vp[4] = {0.f,0.f,0.f,0.f};
      #pragma unroll
      for (int tn = 0; tn < 8; tn++) u3r[tn] = u3g[16*tn + m15];
      #pragma unroll
      for (int tn = 0; tn < 8; tn++){
        short8 b0 = *(const short8*)&xT[(16*tn + m15)*72 + q*8];
        short8 b1 = *(const short8*)&xT[(16*tn + m15)*72 + 32 + q*8];
        floatx4 acc = {0.f,0.f,0.f,0.f};
        acc = __builtin_amdgcn_mfma_f32_16x16x32_bf16(a0, b0, acc, 0,0,0);
        acc = __builtin_amdgcn_mfma_f32_16x16x32_bf16(a1, b1, acc, 0,0,0);
        float e0 = acc[0]*invd[0], e1 = acc[1]*invd[1];
        float e2 = acc[2]*invd[2], e3 = acc[3]*invd[3];
        vp[0] += e0*u3r[tn]; vp[1] += e1*u3r[tn];
        vp[2] += e2*u3r[tn]; vp[3] += e3*u3r[tn];
        uint2 pk; pk.x = packbf(e0, e1); pk.y = packbf(e2, e3);
        *(uint2*)&edgeT[(16*tn + m15)*136 + 16*tm + 4*q] = pk;
      }
      #pragma unroll
      for (int off = 1; off < 16; off <<= 1){
        #pragma unroll
        for (int rr = 0; rr < 4; rr++) vp[rr] += __shfl_xor(vp[rr], off);
      }
      if (m15 == 0){
        #pragma unroll
        for (int rr = 0; rr < 4; rr++) vev[16*tm + 4*q + rr] = vp[rr];
      }
    }
    __syncthreads();

    // ---- E: PN' = mask .* exp(lrelu(vn+ve)) (unnormalized) ----
    {
      const int j  = tid >> 3;
      const int ib = (tid & 7) << 4;
      const uint_t bits = (uint_t)((adjTb[2*j + (ib >> 6)] >> (ib & 63)) & 0xFFFFull);
      const float vnj = vnv[j];
      uint_t pk[8];
      #pragma unroll
      for (int t = 0; t < 8; t++){
        float t0 = lrelu(vnj + vev[ib + 2*t]);
        float t1 = lrelu(vnj + vev[ib + 2*t+1]);
        float v0 = ((bits >> (2*t))   & 1) ? __expf(t0) : 0.f;
        float v1 = ((bits >> (2*t+1)) & 1) ? __expf(t1) : 0.f;
        pk[t] = packbf(v0, v1);
      }
      *(uint4*)&attU[j*136 + ib]     = *(uint4*)&pk[0];
      *(uint4*)&attU[j*136 + ib + 8] = *(uint4*)&pk[4];
    }
    __syncthreads();

    // ---- F1: G = att_n_norm @ tmp (denomN via ones-MFMA).
    //      l0: G is the node output -> +res, pack to xT.
    //      l1: pack normalized G (no res) into Gbuf for F2. ----
    {
      const int tn = wave;
      short8 bb0 = *(const short8*)&edgeT[(16*tn + m15)*136 +  0 + q*8];
      short8 bb1 = *(const short8*)&edgeT[(16*tn + m15)*136 + 32 + q*8];
      short8 bb2 = *(const short8*)&edgeT[(16*tn + m15)*136 + 64 + q*8];
      short8 bb3 = *(const short8*)&edgeT[(16*tn + m15)*136 + 96 + q*8];
      const int dcol = 16*tn + m15;
      #pragma unroll
      for (int tm = 0; tm < 4; tm++){
        const ushort_t* ar = &attU[(16*tm + m15)*136 + q*8];
        const short8 p0 = *(const short8*)(ar +  0);
        const short8 p1 = *(const short8*)(ar + 32);
        const short8 p2 = *(const short8*)(ar + 64);
        const short8 p3 = *(const short8*)(ar + 96);
        floatx4 acc  = {0.f,0.f,0.f,0.f};
        floatx4 accN = {0.f,0.f,0.f,0.f};
        acc  = __builtin_amdgcn_mfma_f32_16x16x32_bf16(p0, bb0, acc, 0,0,0);
        acc  = __builtin_amdgcn_mfma_f32_16x16x32_bf16(p1, bb1, acc, 0,0,0);
        acc  = __builtin_amdgcn_mfma_f32_16x16x32_bf16(p2, bb2, acc, 0,0,0);
        acc  = __builtin_amdgcn_mfma_f32_16x16x32_bf16(p3, bb3, acc, 0,0,0);
        accN = __builtin_amdgcn_mfma_f32_16x16x32_bf16(p0, ones, accN, 0,0,0);
        accN = __builtin_amdgcn_mfma_f32_16x16x32_bf16(p1, ones, accN, 0,0,0);
        accN = __builtin_amdgcn_mfma_f32_16x16x32_bf16(p2, ones, accN, 0,0,0);
        accN = __builtin_amdgcn_mfma_f32_16x16x32_bf16(p3, ones, accN, 0,0,0);
        if (l == 0){
          float v[4];
          #pragma unroll
          for (int rr = 0; rr < 4; rr++)
            v[rr] = acc[rr]*(1.f/accN[rr]) + resreg[tm*4 + rr];
          uint2 pk; pk.x = packbf(v[0], v[1]); pk.y = packbf(v[2], v[3]);
          *(uint2*)&xT[dcol*72 + 16*tm + 4*q] = pk;
        } else {
          #pragma unroll
          for (int rr = 0; rr < 4; rr++)
            Gbuf[(16*tm + 4*q + rr)*136 + dcol] = f2bf(acc[rr]*(1.f/accN[rr]));
        }
      }
    }
    if (l == 1){
      __syncthreads();
      // ---- F2: node = G @ W + residual -> resf (B-frags from global wt) ----
      const int dcol = 16*wave + m15;
      const ushort_t* wr = wt + dcol*128 + q*8;
      const short8 w0 = *(const short8*)(wr +  0);
      const short8 w1 = *(const short8*)(wr + 32);
      const short8 w2 = *(const short8*)(wr + 64);
      const short8 w3 = *(const short8*)(wr + 96);
      #pragma unroll
      for (int tm = 0; tm < 4; tm++){
        const ushort_t* gr = &Gbuf[(16*tm + m15)*136 + q*8];
        floatx4 acc = {0.f,0.f,0.f,0.f};
        acc = __builtin_amdgcn_mfma_f32_16x16x32_bf16(*(const short8*)(gr +  0), w0, acc, 0,0,0);
        acc = __builtin_amdgcn_mfma_f32_16x16x32_bf16(*(const short8*)(gr + 32), w1, acc, 0,0,0);
        acc = __builtin_amdgcn_mfma_f32_16x16x32_bf16(*(const short8*)(gr + 64), w2, acc, 0,0,0);
        acc = __builtin_amdgcn_mfma_f32_16x16x32_bf16(*(const short8*)(gr + 96), w3, acc, 0,0,0);
        #pragma unroll
        for (int rr = 0; rr < 4; rr++)
          resf[(16*tm + 4*q + rr)*132 + dcol] = acc[rr] + resreg[tm*4 + rr];
      }
    }
    __syncthreads();
  }

  // ---- coalesced writeout of both x copies from LDS ----
  for (int p = tid; p < 2048; p += NT){
    int j = p >> 5, c4 = p & 31;
    const float4 w = *(const float4*)&resf[j*132 + c4*4];
    size_t o = (size_t)b*8192 + (size_t)p*4;
    *(float4*)(out + o)       = w;
    *(float4*)(out + BLD + o) = w;
  }
}

extern "C" void kernel_launch(void* const* d_in, const int* in_sizes, int n_in,
                              void* d_out, int out_size, void* d_ws, size_t ws_size,
                              hipStream_t stream){
  (void)in_sizes; (void)n_in; (void)out_size; (void)ws_size;
  // setup_inputs order: 0 inputs, 1 HT, 2 G, 3 EG, 4 emb, 5 emb2,
  //                     6 g1_w2, 7 g1_w3, 8 g1_q, 9 g1_a, 10 g1_a2,
  //                     11 g2_w, 12 g2_w2, 13 g2_w3, 14 g2_q, 15 g2_a, 16 g2_a2
  prep<<<dim3(16), dim3(256), 0, stream>>>(
      (const float*)d_in[6],  (const float*)d_in[7],  (const float*)d_in[8],
      (const float*)d_in[9],  (const float*)d_in[10],
      (const float*)d_in[11], (const float*)d_in[12], (const float*)d_in[13],
      (const float*)d_in[14], (const float*)d_in[15], (const float*)d_in[16],
      d_ws);
  hgat<<<dim3(Bb), dim3(NT), 0, stream>>>(
      (const int*)d_in[0],
      (const float*)d_in[1],
      (const float*)d_in[4],
      (const float*)d_in[5],
      d_ws,
      (float*)d_out);
}